// Round 7
// baseline (369.614 us; speedup 1.0000x reference)
//
#include <hip/hip_runtime.h>
#include <stdint.h>

#define NNODES 50000
#define NEDGES 800000
#define NB ((NNODES + 255) / 256)          // 196 dst-buckets (dst>>8); nodes align to buckets
#define EPB 4096                           // edges per scatter block
#define SCAT_NBLK ((NEDGES + EPB - 1) / EPB)  // 196

typedef __attribute__((ext_vector_type(8))) short bf16x8;
typedef __attribute__((ext_vector_type(4))) float f32x4;

__device__ inline unsigned short f2bf(float f) {
    unsigned u = __float_as_uint(f);
    return (unsigned short)((u + 0x7fffu + ((u >> 16) & 1u)) >> 16);
}
__device__ inline float bf2f(unsigned short h) {
    return __uint_as_float(((unsigned)h) << 16);
}

// ---------------- bucketed CSR build ----------------
// src < 65536 so an edge packs as (dst&255)<<16 | src in one uint32; col stored as ushort.

__global__ void zero_kernel(int* __restrict__ p, int n) {
    int i = blockIdx.x * blockDim.x + threadIdx.x;
    if (i < n) p[i] = 0;
}

__global__ __launch_bounds__(256) void bucket_count_kernel(const int* __restrict__ dst,
                                                           int* __restrict__ bhist) {
    __shared__ int h[NB];
    for (int b = threadIdx.x; b < NB; b += 256) h[b] = 0;
    __syncthreads();
    const int base = blockIdx.x * EPB;
#pragma unroll
    for (int i = 0; i < EPB / 256; ++i) {
        const int e = base + threadIdx.x + i * 256;
        if (e < NEDGES) atomicAdd(&h[dst[e] >> 8], 1);
    }
    __syncthreads();
    for (int b = threadIdx.x; b < NB; b += 256)
        if (h[b]) atomicAdd(&bhist[b], h[b]);
}

__global__ __launch_bounds__(256) void bucket_scan_kernel(const int* __restrict__ bhist,
                                                          int* __restrict__ bofs,
                                                          int* __restrict__ gcur,
                                                          int* __restrict__ rp_last) {
    __shared__ int s[256];
    const int t = threadIdx.x;
    s[t] = (t < NB) ? bhist[t] : 0;
    __syncthreads();
    for (int off = 1; off < 256; off <<= 1) {
        int v = (t >= off) ? s[t - off] : 0;
        __syncthreads();
        s[t] += v;
        __syncthreads();
    }
    if (t < NB) {
        const int excl = (t > 0) ? s[t - 1] : 0;
        bofs[t] = excl;
        gcur[t] = excl;
    }
    if (t == 255) { bofs[NB] = s[255]; rp_last[0] = s[255]; }
}

__global__ __launch_bounds__(256) void bucket_scatter_kernel(const int* __restrict__ src,
                                                             const int* __restrict__ dst,
                                                             int* __restrict__ gcur,
                                                             unsigned* __restrict__ gpk) {
    __shared__ int h[256];
    __shared__ int s[256];
    __shared__ int gof[256];
    __shared__ unsigned pr[EPB];
    __shared__ int ga[EPB];

    const int t = threadIdx.x;
    const int base = blockIdx.x * EPB;
    const int nval = min(EPB, NEDGES - base);

    h[t] = 0;
    __syncthreads();
#pragma unroll
    for (int i = 0; i < EPB / 256; ++i) {
        const int e = base + t + i * 256;
        if (e < NEDGES) atomicAdd(&h[dst[e] >> 8], 1);
    }
    __syncthreads();
    s[t] = h[t];
    __syncthreads();
    for (int off = 1; off < 256; off <<= 1) {
        int v = (t >= off) ? s[t - off] : 0;
        __syncthreads();
        s[t] += v;
        __syncthreads();
    }
    {
        const int c = h[t];
        if (t < NB && c > 0) gof[t] = atomicAdd(&gcur[t], c);
        const int lofs = s[t] - c;
        h[t] = lofs;
        s[t] = lofs;
    }
    __syncthreads();
#pragma unroll
    for (int i = 0; i < EPB / 256; ++i) {
        const int e = base + t + i * 256;
        if (e < NEDGES) {
            const int d = dst[e];
            const int b = d >> 8;
            const int slot = atomicAdd(&h[b], 1);
            pr[slot] = ((unsigned)(d & 255) << 16) | (unsigned)src[e];
            ga[slot] = gof[b] + (slot - s[b]);
        }
    }
    __syncthreads();
#pragma unroll
    for (int i = 0; i < EPB / 256; ++i) {
        const int slot = t + i * 256;
        if (slot < nval) gpk[ga[slot]] = pr[slot];
    }
}

// Pass 4: per-bucket degree hist + scan -> rp/dinv, col fill (16-bit col)
__global__ __launch_bounds__(256) void csr_fill_kernel(const unsigned* __restrict__ gpk,
                                                       const int* __restrict__ bofs,
                                                       int* __restrict__ rp,
                                                       float* __restrict__ dinv,
                                                       unsigned short* __restrict__ col) {
    __shared__ int c[256];
    __shared__ int s[256];
    __shared__ int cur[256];
    const int t = threadIdx.x;
    const int b = blockIdx.x;
    const int beg = bofs[b], end = bofs[b + 1];
    c[t] = 0;
    __syncthreads();
    for (int e = beg + t; e < end; e += 256) atomicAdd(&c[gpk[e] >> 16], 1);
    __syncthreads();
    s[t] = c[t];
    __syncthreads();
    for (int off = 1; off < 256; off <<= 1) {
        int v = (t >= off) ? s[t - off] : 0;
        __syncthreads();
        s[t] += v;
        __syncthreads();
    }
    const int excl = s[t] - c[t];
    cur[t] = excl;
    const int node = b * 256 + t;
    if (node < NNODES) {
        rp[node] = beg + excl;
        dinv[node] = rsqrtf((float)(c[t] + 1));   // +1 self loop
    }
    __syncthreads();
    for (int e = beg + t; e < end; e += 256) {
        const unsigned p = gpk[e];
        const int r = atomicAdd(&cur[p >> 16], 1);
        col[beg + r] = (unsigned short)(p & 0xffffu);
    }
}

// ---------------- x -> premultiplied bf16 mirror: xbf[i] = bf16(dinv[row]*x[i]) ----

__global__ __launch_bounds__(256) void cvt_kernel(const float* __restrict__ in,
                                                  const float* __restrict__ dinv,
                                                  unsigned short* __restrict__ out, int n4) {
    int i = blockIdx.x * 256 + threadIdx.x;
    if (i >= n4) return;
    const float dv = dinv[i >> 5];                 // 32 float4-groups per 128-row
    float4 v = *(const float4*)(in + (size_t)i * 4);
    ushort4 h;
    h.x = f2bf(dv * v.x); h.y = f2bf(dv * v.y); h.z = f2bf(dv * v.z); h.w = f2bf(dv * v.w);
    *(ushort4*)(out + (size_t)i * 4) = h;
}

// ---------------- gather aggregation (premultiplied mirrors) ----------------
// out[d] = dinv[d] * ( dinv[d]*in32[d] + sum_s mirror[s] ) [+bias][relu]
// F=128: wave per dst; lanes 0-31 edge j, lanes 32-63 edge j+1 (ushort4/lane = 512B/instr)

template <bool RELU, bool HAS_BIAS>
__global__ __launch_bounds__(256) void agg128_kernel(const float* __restrict__ in32,
                                                     const unsigned short* __restrict__ inbf,
                                                     float* __restrict__ out,
                                                     const int* __restrict__ rp,
                                                     const unsigned short* __restrict__ col,
                                                     const float* __restrict__ dinv,
                                                     const float* __restrict__ bias) {
    const int wave = threadIdx.x >> 6;
    const int lane = threadIdx.x & 63;
    const int d = blockIdx.x * 4 + wave;
    if (d >= NNODES) return;
    const int half = lane >> 5;
    const int fl = lane & 31;
    const float dv = dinv[d];

    float acc[4] = {0.f, 0.f, 0.f, 0.f};
    if (half == 0) {
        float4 s = *(const float4*)(in32 + (size_t)d * 128 + fl * 4);
        acc[0] = dv * s.x; acc[1] = dv * s.y; acc[2] = dv * s.z; acc[3] = dv * s.w;
    }

    int j = rp[d] + half;
    const int end = rp[d + 1];
    for (; j + 2 < end; j += 4) {
        const int c0 = col[j], c1 = col[j + 2];
        ushort4 a0 = *(const ushort4*)(inbf + (size_t)c0 * 128 + fl * 4);
        ushort4 a1 = *(const ushort4*)(inbf + (size_t)c1 * 128 + fl * 4);
        acc[0] += bf2f(a0.x) + bf2f(a1.x);
        acc[1] += bf2f(a0.y) + bf2f(a1.y);
        acc[2] += bf2f(a0.z) + bf2f(a1.z);
        acc[3] += bf2f(a0.w) + bf2f(a1.w);
    }
    if (j < end) {
        const int c0 = col[j];
        ushort4 a0 = *(const ushort4*)(inbf + (size_t)c0 * 128 + fl * 4);
        acc[0] += bf2f(a0.x); acc[1] += bf2f(a0.y); acc[2] += bf2f(a0.z); acc[3] += bf2f(a0.w);
    }

#pragma unroll
    for (int v = 0; v < 4; ++v) acc[v] += __shfl_down(acc[v], 32);

    if (half == 0) {
        float4 r;
        float* pr = &r.x;
#pragma unroll
        for (int v = 0; v < 4; ++v) {
            float t = dv * acc[v];
            if constexpr (HAS_BIAS) t += bias[fl * 4 + v];
            if constexpr (RELU) t = fmaxf(t, 0.0f);
            pr[v] = t;
        }
        *(float4*)(out + (size_t)d * 128 + fl * 4) = r;
    }
}

// F=64: wave per dst; 4 quarter-waves process edges j, j+1, j+2, j+3
template <bool RELU, bool HAS_BIAS>
__global__ __launch_bounds__(256) void agg64_kernel(const float* __restrict__ in32,
                                                    const unsigned short* __restrict__ inbf,
                                                    float* __restrict__ out,
                                                    const int* __restrict__ rp,
                                                    const unsigned short* __restrict__ col,
                                                    const float* __restrict__ dinv,
                                                    const float* __restrict__ bias) {
    const int wave = threadIdx.x >> 6;
    const int lane = threadIdx.x & 63;
    const int d = blockIdx.x * 4 + wave;
    if (d >= NNODES) return;
    const int quarter = lane >> 4;
    const int fl = lane & 15;
    const float dv = dinv[d];

    float acc[4] = {0.f, 0.f, 0.f, 0.f};
    if (quarter == 0) {
        float4 s = *(const float4*)(in32 + (size_t)d * 64 + fl * 4);
        acc[0] = dv * s.x; acc[1] = dv * s.y; acc[2] = dv * s.z; acc[3] = dv * s.w;
    }

    int j = rp[d] + quarter;
    const int end = rp[d + 1];
    for (; j + 4 < end; j += 8) {
        const int c0 = col[j], c1 = col[j + 4];
        ushort4 a0 = *(const ushort4*)(inbf + (size_t)c0 * 64 + fl * 4);
        ushort4 a1 = *(const ushort4*)(inbf + (size_t)c1 * 64 + fl * 4);
        acc[0] += bf2f(a0.x) + bf2f(a1.x);
        acc[1] += bf2f(a0.y) + bf2f(a1.y);
        acc[2] += bf2f(a0.z) + bf2f(a1.z);
        acc[3] += bf2f(a0.w) + bf2f(a1.w);
    }
    if (j < end) {
        const int c0 = col[j];
        ushort4 a0 = *(const ushort4*)(inbf + (size_t)c0 * 64 + fl * 4);
        acc[0] += bf2f(a0.x); acc[1] += bf2f(a0.y); acc[2] += bf2f(a0.z); acc[3] += bf2f(a0.w);
    }

#pragma unroll
    for (int v = 0; v < 4; ++v) {
        acc[v] += __shfl_down(acc[v], 32);
        acc[v] += __shfl_down(acc[v], 16);
    }

    if (quarter == 0) {
        float4 r;
        float* pr = &r.x;
#pragma unroll
        for (int v = 0; v < 4; ++v) {
            float t = dv * acc[v];
            if constexpr (HAS_BIAS) t += bias[fl * 4 + v];
            if constexpr (RELU) t = fmaxf(t, 0.0f);
            pr[v] = t;
        }
        *(float4*)(out + (size_t)d * 64 + fl * 4) = r;
    }
}

// F=40 (final layer): wave per dst, lanes 0-39, scalar elems
__global__ __launch_bounds__(256) void agg40_kernel(const float* __restrict__ in32,
                                                    const unsigned short* __restrict__ inbf,
                                                    float* __restrict__ out,
                                                    const int* __restrict__ rp,
                                                    const unsigned short* __restrict__ col,
                                                    const float* __restrict__ dinv,
                                                    const float* __restrict__ bias) {
    const int wave = threadIdx.x >> 6;
    const int lane = threadIdx.x & 63;
    const int d = blockIdx.x * 4 + wave;
    if (d >= NNODES) return;
    if (lane >= 40) return;
    const float dv = dinv[d];

    float acc = dv * in32[(size_t)d * 40 + lane];
    int j = rp[d];
    const int end = rp[d + 1];
    for (; j + 2 <= end; j += 2) {
        const int c0 = col[j], c1 = col[j + 1];
        acc += bf2f(inbf[(size_t)c0 * 40 + lane]) + bf2f(inbf[(size_t)c1 * 40 + lane]);
    }
    if (j < end) acc += bf2f(inbf[(size_t)col[j] * 40 + lane]);

    out[(size_t)d * 40 + lane] = dv * acc + bias[lane];
}

// ---------------- weight repack: W[K][M] fp32 -> split-bf16 fragment order ----

template <int K, int M>
__global__ __launch_bounds__(256) void repack_kernel(const float* __restrict__ W,
                                                     unsigned short* __restrict__ hi,
                                                     unsigned short* __restrict__ lo) {
    int i = blockIdx.x * 256 + threadIdx.x;
    if (i >= K * M) return;
    const int k = i / M, n = i % M;
    constexpr int KS = K / 32;
    const int cb = n >> 7;
    const int ct = (n >> 4) & 7;
    const int ln = ((k >> 3) & 3) * 16 + (n & 15);
    const int j  = k & 7;
    const int ks = k >> 5;
    const size_t o = ((((size_t)cb * KS + ks) * 8 + ct) * 64 + ln) * 8 + j;
    const float f = W[i];
    const unsigned short h = f2bf(f);
    hi[o] = h;
    lo[o] = f2bf(f - bf2f(h));
}

// ---------------- split-bf16 MFMA GEMM ----------------
// BM=64: 4 waves in 1x4, each 64x32. bf mirror premultiplied by dinv[row].

template <int K, int M, int BM, bool BIAS_RELU, bool WRITE_BF>
__global__ __launch_bounds__(256) void mfma_gemm_kernel(const float* __restrict__ A,
                                                        const unsigned short* __restrict__ Whi,
                                                        const unsigned short* __restrict__ Wlo,
                                                        const float* __restrict__ bias,
                                                        float* __restrict__ C,
                                                        unsigned short* __restrict__ Cbf,
                                                        const float* __restrict__ dinv) {
    constexpr int KS = K / 32;
    constexpr int ASZ = BM * 64;
    constexpr int CI = (BM == 128) ? 4 : 2;
    __shared__ char lds[2 * ASZ + 16384];
    char* Ahi = lds;
    char* Alo = lds + ASZ;
    char* Bhi = lds + 2 * ASZ;
    char* Blo = lds + 2 * ASZ + 8192;

    const int t = threadIdx.x;
    const int lane = t & 63;
    const int w = t >> 6;
    const int wr = (BM == 128) ? (w >> 1) : 0;
    const int wc = (BM == 128) ? (w & 1) : w;
    const int r0 = blockIdx.x * BM;
    const int n0 = blockIdx.y * 128;

    const unsigned short* bhg = Whi + (size_t)blockIdx.y * KS * 4096;
    const unsigned short* blg = Wlo + (size_t)blockIdx.y * KS * 4096;

    f32x4 acc[4][CI];
#pragma unroll
    for (int i = 0; i < 4; ++i)
#pragma unroll
        for (int j = 0; j < CI; ++j) acc[i][j] = (f32x4){0.f, 0.f, 0.f, 0.f};

    for (int ks = 0; ks < KS; ++ks) {
        const int k0 = ks * 32;

        {
            const char* gh = (const char*)(bhg + (size_t)ks * 4096);
            const char* gl = (const char*)(blg + (size_t)ks * 4096);
#pragma unroll
            for (int c = 0; c < 2; ++c) {
                const int ct = w * 2 + c;
                __builtin_amdgcn_global_load_lds(
                    (const __attribute__((address_space(1))) void*)(gh + ct * 1024 + lane * 16),
                    (__attribute__((address_space(3))) void*)(Bhi + ct * 1024), 16, 0, 0);
                __builtin_amdgcn_global_load_lds(
                    (const __attribute__((address_space(1))) void*)(gl + ct * 1024 + lane * 16),
                    (__attribute__((address_space(3))) void*)(Blo + ct * 1024), 16, 0, 0);
            }
        }

        float4 av[BM / 32];
#pragma unroll
        for (int i = 0; i < BM / 32; ++i) {
            const int q = t + i * 256;
            const int row = q >> 3;
            const int kq = (q & 7) * 4;
            const int gr = r0 + row;
            float4 v = make_float4(0.f, 0.f, 0.f, 0.f);
            if (gr < NNODES) v = *(const float4*)(A + (size_t)gr * K + k0 + kq);
            av[i] = v;
        }
#pragma unroll
        for (int i = 0; i < BM / 32; ++i) {
            const int q = t + i * 256;
            const int row = q >> 3;
            const int kq = (q & 7) * 4;
            const int rt = row >> 4, m = row & 15, quad = kq >> 3, j0 = kq & 7;
            const int off = rt * 1024 + (quad * 16 + m) * 16 + j0 * 2;
            const float4 v = av[i];
            ushort4 h, l;
            h.x = f2bf(v.x); l.x = f2bf(v.x - bf2f(h.x));
            h.y = f2bf(v.y); l.y = f2bf(v.y - bf2f(h.y));
            h.z = f2bf(v.z); l.z = f2bf(v.z - bf2f(h.z));
            h.w = f2bf(v.w); l.w = f2bf(v.w - bf2f(h.w));
            *(ushort4*)(Ahi + off) = h;
            *(ushort4*)(Alo + off) = l;
        }
        __syncthreads();

        bf16x8 ah[4], al[4], bh[CI], bl[CI];
#pragma unroll
        for (int i = 0; i < 4; ++i) {
            ah[i] = *(const bf16x8*)(Ahi + (wr * 4 + i) * 1024 + lane * 16);
            al[i] = *(const bf16x8*)(Alo + (wr * 4 + i) * 1024 + lane * 16);
        }
#pragma unroll
        for (int j = 0; j < CI; ++j) {
            bh[j] = *(const bf16x8*)(Bhi + (wc * CI + j) * 1024 + lane * 16);
            bl[j] = *(const bf16x8*)(Blo + (wc * CI + j) * 1024 + lane * 16);
        }
#pragma unroll
        for (int i = 0; i < 4; ++i)
#pragma unroll
            for (int j = 0; j < CI; ++j) {
                acc[i][j] = __builtin_amdgcn_mfma_f32_16x16x32_bf16(ah[i], bh[j], acc[i][j], 0, 0, 0);
                acc[i][j] = __builtin_amdgcn_mfma_f32_16x16x32_bf16(ah[i], bl[j], acc[i][j], 0, 0, 0);
                acc[i][j] = __builtin_amdgcn_mfma_f32_16x16x32_bf16(al[i], bh[j], acc[i][j], 0, 0, 0);
            }
        __syncthreads();
    }

    const int quad = lane >> 4;
    const int cl = lane & 15;
#pragma unroll
    for (int i = 0; i < 4; ++i) {
#pragma unroll
        for (int j = 0; j < CI; ++j) {
            const int colg = n0 + wc * (CI * 16) + j * 16 + cl;
            float bv = 0.f;
            if constexpr (BIAS_RELU) bv = bias[colg];
#pragma unroll
            for (int r = 0; r < 4; ++r) {
                const int rowg = r0 + wr * 64 + i * 16 + quad * 4 + r;
                if (rowg < NNODES) {
                    float v = acc[i][j][r] + bv;
                    if constexpr (BIAS_RELU) v = fmaxf(v, 0.f);
                    C[(size_t)rowg * M + colg] = v;
                    if constexpr (WRITE_BF) Cbf[(size_t)rowg * M + colg] = f2bf(dinv[rowg] * v);
                }
            }
        }
    }
}

// ---------------- fp32 register-tiled GEMM (layers 3-4) ----------------

template <int BM, int BN, int BK, int TM, int TN, bool BIAS_RELU, bool WRITE_BF>
__global__ __launch_bounds__(256) void gemm_kernel(const float* __restrict__ A,
                                                   const float* __restrict__ W,
                                                   const float* __restrict__ bias,
                                                   float* __restrict__ C,
                                                   unsigned short* __restrict__ Cbf,
                                                   const float* __restrict__ dinv,
                                                   int Nrows, int K, int M) {
    constexpr int TX = BN / TN;
    constexpr int TY = BM / TM;
    static_assert(TX * TY == 256, "thread grid must be 256");
    constexpr int A_LOADS = (BM * BK) / (256 * 4);
    constexpr int W_LOADS = (BN * BK) / (256 * 4);
    static_assert(A_LOADS >= 1 && W_LOADS >= 1, "tile too small");

    const int tid = threadIdx.x;
    const int tx = tid % TX;
    const int ty = tid / TX;
    const int r0 = blockIdx.x * BM;
    const int c0 = blockIdx.y * BN;

    __shared__ float As[BK][BM + 4];
    __shared__ float Ws[BK][BN];

    float acc[TM][TN] = {};

    for (int k0 = 0; k0 < K; k0 += BK) {
#pragma unroll
        for (int l = 0; l < A_LOADS; ++l) {
            const int idx = tid + l * 256;
            const int row = idx / (BK / 4);
            const int kq = idx % (BK / 4);
            float4 v = make_float4(0.f, 0.f, 0.f, 0.f);
            const int gr = r0 + row;
            if (gr < Nrows) v = *(const float4*)(A + (size_t)gr * K + k0 + kq * 4);
            As[kq * 4 + 0][row] = v.x;
            As[kq * 4 + 1][row] = v.y;
            As[kq * 4 + 2][row] = v.z;
            As[kq * 4 + 3][row] = v.w;
        }
#pragma unroll
        for (int l = 0; l < W_LOADS; ++l) {
            const int idx = tid + l * 256;
            const int kk = idx / (BN / 4);
            const int cq = idx % (BN / 4);
            const int gc = c0 + cq * 4;
            float4 v;
            const float* wrow = W + (size_t)(k0 + kk) * M;
            if (gc + 3 < M) {
                v = *(const float4*)(wrow + gc);
            } else {
                v.x = (gc + 0 < M) ? wrow[gc + 0] : 0.f;
                v.y = (gc + 1 < M) ? wrow[gc + 1] : 0.f;
                v.z = (gc + 2 < M) ? wrow[gc + 2] : 0.f;
                v.w = (gc + 3 < M) ? wrow[gc + 3] : 0.f;
            }
            *(float4*)&Ws[kk][cq * 4] = v;
        }
        __syncthreads();

#pragma unroll
        for (int kk = 0; kk < BK; ++kk) {
            float a[TM], b[TN];
#pragma unroll
            for (int i = 0; i < TM; ++i) a[i] = As[kk][ty * TM + i];
#pragma unroll
            for (int j = 0; j < TN; ++j) b[j] = Ws[kk][tx * TN + j];
#pragma unroll
            for (int i = 0; i < TM; ++i)
#pragma unroll
                for (int j = 0; j < TN; ++j) acc[i][j] += a[i] * b[j];
        }
        __syncthreads();
    }

#pragma unroll
    for (int i = 0; i < TM; ++i) {
        const int gr = r0 + ty * TM + i;
        if (gr >= Nrows) continue;
        const float dvr = WRITE_BF ? dinv[gr] : 0.f;
#pragma unroll
        for (int j = 0; j < TN; ++j) {
            const int gc = c0 + tx * TN + j;
            if (gc >= M) continue;
            float v = acc[i][j];
            if constexpr (BIAS_RELU) v = fmaxf(v + bias[gc], 0.0f);
            C[(size_t)gr * M + gc] = v;
            if constexpr (WRITE_BF) Cbf[(size_t)gr * M + gc] = f2bf(dvr * v);
        }
    }
}

// ---------------- launch ----------------

extern "C" void kernel_launch(void* const* d_in, const int* in_sizes, int n_in,
                              void* d_out, int out_size, void* d_ws, size_t ws_size,
                              hipStream_t stream) {
    const float* x  = (const float*)d_in[0];
    const int* ei   = (const int*)d_in[1];
    const float* W1 = (const float*)d_in[2];
    const float* b1 = (const float*)d_in[3];
    const float* W2 = (const float*)d_in[4];
    const float* b2 = (const float*)d_in[5];
    const float* W3 = (const float*)d_in[6];
    const float* b3 = (const float*)d_in[7];
    const float* W4 = (const float*)d_in[8];
    const float* b4 = (const float*)d_in[9];
    float* out = (float*)d_out;
    const int* esrc = ei;
    const int* edst = ei + NEDGES;

    char* w = (char*)d_ws;
    auto alloc = [&](size_t bytes) -> void* {
        void* p = (void*)w;
        w += (bytes + 255) & ~(size_t)255;
        return p;
    };
    int* rp     = (int*)alloc((size_t)(NNODES + 1) * 4);
    unsigned short* col = (unsigned short*)alloc((size_t)NEDGES * 2);
    float* dinv = (float*)alloc((size_t)NNODES * 4);
    int* bhist  = (int*)alloc((size_t)NB * 4);
    int* bofs   = (int*)alloc((size_t)(NB + 1) * 4);
    int* gcur   = (int*)alloc((size_t)NB * 4);
    unsigned* gpk = (unsigned*)alloc((size_t)NEDGES * 4);
    unsigned short* W1hi = (unsigned short*)alloc((size_t)128 * 256 * 2);
    unsigned short* W1lo = (unsigned short*)alloc((size_t)128 * 256 * 2);
    unsigned short* W2hi = (unsigned short*)alloc((size_t)256 * 128 * 2);
    unsigned short* W2lo = (unsigned short*)alloc((size_t)256 * 128 * 2);
    float* B0   = (float*)alloc((size_t)NNODES * 256 * 4);
    float* B1   = (float*)alloc((size_t)NNODES * 128 * 4);
    float* B2   = (float*)alloc((size_t)NNODES * 128 * 4);
    unsigned short* xbf  = (unsigned short*)alloc((size_t)NNODES * 128 * 2);
    unsigned short* B1bf = (unsigned short*)alloc((size_t)NNODES * 128 * 2);
    unsigned short* B0bf = (unsigned short*)alloc((size_t)NNODES * 64 * 2);

    // weight repack (tiny, independent)
    repack_kernel<128, 256><<<(128 * 256 + 255) / 256, 256, 0, stream>>>(W1, W1hi, W1lo);
    repack_kernel<256, 128><<<(256 * 128 + 255) / 256, 256, 0, stream>>>(W2, W2hi, W2lo);

    // bucketed CSR build (5 dispatches) — produces rp, col16, dinv
    zero_kernel<<<1, 256, 0, stream>>>(bhist, NB);
    bucket_count_kernel<<<SCAT_NBLK, 256, 0, stream>>>(edst, bhist);
    bucket_scan_kernel<<<1, 256, 0, stream>>>(bhist, bofs, gcur, rp + NNODES);
    bucket_scatter_kernel<<<SCAT_NBLK, 256, 0, stream>>>(esrc, edst, gcur, gpk);
    csr_fill_kernel<<<NB, 256, 0, stream>>>(gpk, bofs, rp, dinv, col);

    // x mirror premultiplied by dinv (needs dinv)
    cvt_kernel<<<(NNODES * 128 / 4 + 255) / 256, 256, 0, stream>>>(x, dinv, xbf, NNODES * 128 / 4);

    const int aggGrid = (NNODES + 3) / 4;
    const int rowBlks64 = (NNODES + 63) / 64;   // 782

    // Layer 1: aggregate first (dim 128), then MFMA GEMM 128->256 (+bias+relu)
    agg128_kernel<false, false><<<aggGrid, 256, 0, stream>>>(x, xbf, B2, rp, col, dinv, nullptr);
    mfma_gemm_kernel<128, 256, 64, true, false>
        <<<dim3(rowBlks64, 2), 256, 0, stream>>>(B2, W1hi, W1lo, b1, B0, nullptr, nullptr);

    // Layer 2: MFMA GEMM 256->128 (emit premult bf16 mirror), then aggregate (+bias+relu)
    mfma_gemm_kernel<256, 128, 64, false, true>
        <<<dim3(rowBlks64, 1), 256, 0, stream>>>(B0, W2hi, W2lo, nullptr, B1, B1bf, dinv);
    agg128_kernel<true, true><<<aggGrid, 256, 0, stream>>>(B1, B1bf, B2, rp, col, dinv, b2);

    // Layer 3: fp32 GEMM 128->64 (emit premult mirror), aggregate (+bias+relu)
    gemm_kernel<64, 64, 16, 4, 4, false, true>
        <<<dim3(rowBlks64, 1), 256, 0, stream>>>(B2, W3, nullptr, B0, B0bf, dinv, NNODES, 128, 64);
    agg64_kernel<true, true><<<aggGrid, 256, 0, stream>>>(B0, B0bf, B1, rp, col, dinv, b3);

    // Layer 4: fp32 GEMM 64->40 (emit premult mirror), aggregate (+bias, no relu) -> out
    gemm_kernel<64, 64, 16, 4, 4, false, true>
        <<<dim3(rowBlks64, 1), 256, 0, stream>>>(B1, W4, nullptr, B0, B0bf, dinv, NNODES, 64, 40);
    agg40_kernel<<<aggGrid, 256, 0, stream>>>(B0, B0bf, out, rp, col, dinv, b4);
}

// Round 8
// 350.832 us; speedup vs baseline: 1.0535x; 1.0535x over previous
//
#include <hip/hip_runtime.h>
#include <stdint.h>

#define NNODES 50000
#define NEDGES 800000
#define NB ((NNODES + 255) / 256)          // 196 dst-buckets (dst>>8); nodes align to buckets
#define EPB 4096                           // edges per scatter block
#define SCAT_NBLK ((NEDGES + EPB - 1) / EPB)  // 196

typedef __attribute__((ext_vector_type(8))) short bf16x8;
typedef __attribute__((ext_vector_type(4))) float f32x4;

__device__ inline unsigned short f2bf(float f) {
    unsigned u = __float_as_uint(f);
    return (unsigned short)((u + 0x7fffu + ((u >> 16) & 1u)) >> 16);
}
__device__ inline float bf2f(unsigned short h) {
    return __uint_as_float(((unsigned)h) << 16);
}

// ---------------- bucketed CSR build ----------------
// src < 65536 so an edge packs as (dst&255)<<16 | src in one uint32; col stored as ushort.

__global__ void zero_kernel(int* __restrict__ p, int n) {
    int i = blockIdx.x * blockDim.x + threadIdx.x;
    if (i < n) p[i] = 0;
}

__global__ __launch_bounds__(256) void bucket_count_kernel(const int* __restrict__ dst,
                                                           int* __restrict__ bhist) {
    __shared__ int h[NB];
    for (int b = threadIdx.x; b < NB; b += 256) h[b] = 0;
    __syncthreads();
    const int base = blockIdx.x * EPB;
#pragma unroll
    for (int i = 0; i < EPB / 256; ++i) {
        const int e = base + threadIdx.x + i * 256;
        if (e < NEDGES) atomicAdd(&h[dst[e] >> 8], 1);
    }
    __syncthreads();
    for (int b = threadIdx.x; b < NB; b += 256)
        if (h[b]) atomicAdd(&bhist[b], h[b]);
}

__global__ __launch_bounds__(256) void bucket_scan_kernel(const int* __restrict__ bhist,
                                                          int* __restrict__ bofs,
                                                          int* __restrict__ gcur,
                                                          int* __restrict__ rp_last) {
    __shared__ int s[256];
    const int t = threadIdx.x;
    s[t] = (t < NB) ? bhist[t] : 0;
    __syncthreads();
    for (int off = 1; off < 256; off <<= 1) {
        int v = (t >= off) ? s[t - off] : 0;
        __syncthreads();
        s[t] += v;
        __syncthreads();
    }
    if (t < NB) {
        const int excl = (t > 0) ? s[t - 1] : 0;
        bofs[t] = excl;
        gcur[t] = excl;
    }
    if (t == 255) { bofs[NB] = s[255]; rp_last[0] = s[255]; }
}

__global__ __launch_bounds__(256) void bucket_scatter_kernel(const int* __restrict__ src,
                                                             const int* __restrict__ dst,
                                                             int* __restrict__ gcur,
                                                             unsigned* __restrict__ gpk) {
    __shared__ int h[256];
    __shared__ int s[256];
    __shared__ int gof[256];
    __shared__ unsigned pr[EPB];
    __shared__ int ga[EPB];

    const int t = threadIdx.x;
    const int base = blockIdx.x * EPB;
    const int nval = min(EPB, NEDGES - base);

    h[t] = 0;
    __syncthreads();
#pragma unroll
    for (int i = 0; i < EPB / 256; ++i) {
        const int e = base + t + i * 256;
        if (e < NEDGES) atomicAdd(&h[dst[e] >> 8], 1);
    }
    __syncthreads();
    s[t] = h[t];
    __syncthreads();
    for (int off = 1; off < 256; off <<= 1) {
        int v = (t >= off) ? s[t - off] : 0;
        __syncthreads();
        s[t] += v;
        __syncthreads();
    }
    {
        const int c = h[t];
        if (t < NB && c > 0) gof[t] = atomicAdd(&gcur[t], c);
        const int lofs = s[t] - c;
        h[t] = lofs;
        s[t] = lofs;
    }
    __syncthreads();
#pragma unroll
    for (int i = 0; i < EPB / 256; ++i) {
        const int e = base + t + i * 256;
        if (e < NEDGES) {
            const int d = dst[e];
            const int b = d >> 8;
            const int slot = atomicAdd(&h[b], 1);
            pr[slot] = ((unsigned)(d & 255) << 16) | (unsigned)src[e];
            ga[slot] = gof[b] + (slot - s[b]);
        }
    }
    __syncthreads();
#pragma unroll
    for (int i = 0; i < EPB / 256; ++i) {
        const int slot = t + i * 256;
        if (slot < nval) gpk[ga[slot]] = pr[slot];
    }
}

// Pass 4: per-bucket degree hist + scan -> rp/dinv, col fill (16-bit col)
__global__ __launch_bounds__(256) void csr_fill_kernel(const unsigned* __restrict__ gpk,
                                                       const int* __restrict__ bofs,
                                                       int* __restrict__ rp,
                                                       float* __restrict__ dinv,
                                                       unsigned short* __restrict__ col) {
    __shared__ int c[256];
    __shared__ int s[256];
    __shared__ int cur[256];
    const int t = threadIdx.x;
    const int b = blockIdx.x;
    const int beg = bofs[b], end = bofs[b + 1];
    c[t] = 0;
    __syncthreads();
    for (int e = beg + t; e < end; e += 256) atomicAdd(&c[gpk[e] >> 16], 1);
    __syncthreads();
    s[t] = c[t];
    __syncthreads();
    for (int off = 1; off < 256; off <<= 1) {
        int v = (t >= off) ? s[t - off] : 0;
        __syncthreads();
        s[t] += v;
        __syncthreads();
    }
    const int excl = s[t] - c[t];
    cur[t] = excl;
    const int node = b * 256 + t;
    if (node < NNODES) {
        rp[node] = beg + excl;
        dinv[node] = rsqrtf((float)(c[t] + 1));   // +1 self loop
    }
    __syncthreads();
    for (int e = beg + t; e < end; e += 256) {
        const unsigned p = gpk[e];
        const int r = atomicAdd(&cur[p >> 16], 1);
        col[beg + r] = (unsigned short)(p & 0xffffu);
    }
}

// ---------------- x -> premultiplied bf16 mirror: xbf[i] = bf16(dinv[row]*x[i]) ----

__global__ __launch_bounds__(256) void cvt_kernel(const float* __restrict__ in,
                                                  const float* __restrict__ dinv,
                                                  unsigned short* __restrict__ out, int n4) {
    int i = blockIdx.x * 256 + threadIdx.x;
    if (i >= n4) return;
    const float dv = dinv[i >> 5];                 // 32 float4-groups per 128-row
    float4 v = *(const float4*)(in + (size_t)i * 4);
    ushort4 h;
    h.x = f2bf(dv * v.x); h.y = f2bf(dv * v.y); h.z = f2bf(dv * v.z); h.w = f2bf(dv * v.w);
    *(ushort4*)(out + (size_t)i * 4) = h;
}

// ---------------- gather aggregation (premultiplied mirrors) ----------------
// out[d] = dinv[d] * ( dinv[d]*in32[d] + sum_s mirror[s] ) [+bias][relu]
// F=128: wave per dst; lanes 0-31 edge j, lanes 32-63 edge j+1 (ushort4/lane)

template <bool RELU, bool HAS_BIAS>
__global__ __launch_bounds__(256) void agg128_kernel(const float* __restrict__ in32,
                                                     const unsigned short* __restrict__ inbf,
                                                     float* __restrict__ out,
                                                     const int* __restrict__ rp,
                                                     const unsigned short* __restrict__ col,
                                                     const float* __restrict__ dinv,
                                                     const float* __restrict__ bias) {
    const int wave = threadIdx.x >> 6;
    const int lane = threadIdx.x & 63;
    const int d = blockIdx.x * 4 + wave;
    if (d >= NNODES) return;
    const int half = lane >> 5;
    const int fl = lane & 31;
    const float dv = dinv[d];

    float acc[4] = {0.f, 0.f, 0.f, 0.f};
    if (half == 0) {
        float4 s = *(const float4*)(in32 + (size_t)d * 128 + fl * 4);
        acc[0] = dv * s.x; acc[1] = dv * s.y; acc[2] = dv * s.z; acc[3] = dv * s.w;
    }

    int j = rp[d] + half;
    const int end = rp[d + 1];
    for (; j + 2 < end; j += 4) {
        const int c0 = col[j], c1 = col[j + 2];
        ushort4 a0 = *(const ushort4*)(inbf + (size_t)c0 * 128 + fl * 4);
        ushort4 a1 = *(const ushort4*)(inbf + (size_t)c1 * 128 + fl * 4);
        acc[0] += bf2f(a0.x) + bf2f(a1.x);
        acc[1] += bf2f(a0.y) + bf2f(a1.y);
        acc[2] += bf2f(a0.z) + bf2f(a1.z);
        acc[3] += bf2f(a0.w) + bf2f(a1.w);
    }
    if (j < end) {
        const int c0 = col[j];
        ushort4 a0 = *(const ushort4*)(inbf + (size_t)c0 * 128 + fl * 4);
        acc[0] += bf2f(a0.x); acc[1] += bf2f(a0.y); acc[2] += bf2f(a0.z); acc[3] += bf2f(a0.w);
    }

#pragma unroll
    for (int v = 0; v < 4; ++v) acc[v] += __shfl_down(acc[v], 32);

    if (half == 0) {
        float4 r;
        float* pr = &r.x;
#pragma unroll
        for (int v = 0; v < 4; ++v) {
            float t = dv * acc[v];
            if constexpr (HAS_BIAS) t += bias[fl * 4 + v];
            if constexpr (RELU) t = fmaxf(t, 0.0f);
            pr[v] = t;
        }
        *(float4*)(out + (size_t)d * 128 + fl * 4) = r;
    }
}

// F=64: wave per dst; 4 quarter-waves process interleaved edges.
// Optional premultiplied bf16 mirror of the OUTPUT (for a following aggregate-first layer).
template <bool RELU, bool HAS_BIAS, bool WRITE_BF>
__global__ __launch_bounds__(256) void agg64_kernel(const float* __restrict__ in32,
                                                    const unsigned short* __restrict__ inbf,
                                                    float* __restrict__ out,
                                                    unsigned short* __restrict__ outbf,
                                                    const int* __restrict__ rp,
                                                    const unsigned short* __restrict__ col,
                                                    const float* __restrict__ dinv,
                                                    const float* __restrict__ bias) {
    const int wave = threadIdx.x >> 6;
    const int lane = threadIdx.x & 63;
    const int d = blockIdx.x * 4 + wave;
    if (d >= NNODES) return;
    const int quarter = lane >> 4;
    const int fl = lane & 15;
    const float dv = dinv[d];

    float acc[4] = {0.f, 0.f, 0.f, 0.f};
    if (quarter == 0) {
        float4 s = *(const float4*)(in32 + (size_t)d * 64 + fl * 4);
        acc[0] = dv * s.x; acc[1] = dv * s.y; acc[2] = dv * s.z; acc[3] = dv * s.w;
    }

    int j = rp[d] + quarter;
    const int end = rp[d + 1];
    for (; j + 4 < end; j += 8) {
        const int c0 = col[j], c1 = col[j + 4];
        ushort4 a0 = *(const ushort4*)(inbf + (size_t)c0 * 64 + fl * 4);
        ushort4 a1 = *(const ushort4*)(inbf + (size_t)c1 * 64 + fl * 4);
        acc[0] += bf2f(a0.x) + bf2f(a1.x);
        acc[1] += bf2f(a0.y) + bf2f(a1.y);
        acc[2] += bf2f(a0.z) + bf2f(a1.z);
        acc[3] += bf2f(a0.w) + bf2f(a1.w);
    }
    if (j < end) {
        const int c0 = col[j];
        ushort4 a0 = *(const ushort4*)(inbf + (size_t)c0 * 64 + fl * 4);
        acc[0] += bf2f(a0.x); acc[1] += bf2f(a0.y); acc[2] += bf2f(a0.z); acc[3] += bf2f(a0.w);
    }

#pragma unroll
    for (int v = 0; v < 4; ++v) {
        acc[v] += __shfl_down(acc[v], 32);
        acc[v] += __shfl_down(acc[v], 16);
    }

    if (quarter == 0) {
        float4 r;
        float* pr = &r.x;
#pragma unroll
        for (int v = 0; v < 4; ++v) {
            float t = dv * acc[v];
            if constexpr (HAS_BIAS) t += bias[fl * 4 + v];
            if constexpr (RELU) t = fmaxf(t, 0.0f);
            pr[v] = t;
        }
        *(float4*)(out + (size_t)d * 64 + fl * 4) = r;
        if constexpr (WRITE_BF) {
            ushort4 hb;
            hb.x = f2bf(dv * pr[0]); hb.y = f2bf(dv * pr[1]);
            hb.z = f2bf(dv * pr[2]); hb.w = f2bf(dv * pr[3]);
            *(ushort4*)(outbf + (size_t)d * 64 + fl * 4) = hb;
        }
    }
}

// ---------------- weight repack: W[K][M] fp32 -> split-bf16 fragment order ----

template <int K, int M>
__global__ __launch_bounds__(256) void repack_kernel(const float* __restrict__ W,
                                                     unsigned short* __restrict__ hi,
                                                     unsigned short* __restrict__ lo) {
    int i = blockIdx.x * 256 + threadIdx.x;
    if (i >= K * M) return;
    const int k = i / M, n = i % M;
    constexpr int KS = K / 32;
    const int cb = n >> 7;
    const int ct = (n >> 4) & 7;
    const int ln = ((k >> 3) & 3) * 16 + (n & 15);
    const int j  = k & 7;
    const int ks = k >> 5;
    const size_t o = ((((size_t)cb * KS + ks) * 8 + ct) * 64 + ln) * 8 + j;
    const float f = W[i];
    const unsigned short h = f2bf(f);
    hi[o] = h;
    lo[o] = f2bf(f - bf2f(h));
}

// ---------------- split-bf16 MFMA GEMM ----------------
// BM=64: 4 waves in 1x4, each 64x32. bf mirror premultiplied by dinv[row].

template <int K, int M, int BM, bool BIAS_RELU, bool WRITE_BF>
__global__ __launch_bounds__(256) void mfma_gemm_kernel(const float* __restrict__ A,
                                                        const unsigned short* __restrict__ Whi,
                                                        const unsigned short* __restrict__ Wlo,
                                                        const float* __restrict__ bias,
                                                        float* __restrict__ C,
                                                        unsigned short* __restrict__ Cbf,
                                                        const float* __restrict__ dinv) {
    constexpr int KS = K / 32;
    constexpr int ASZ = BM * 64;
    constexpr int CI = (BM == 128) ? 4 : 2;
    __shared__ char lds[2 * ASZ + 16384];
    char* Ahi = lds;
    char* Alo = lds + ASZ;
    char* Bhi = lds + 2 * ASZ;
    char* Blo = lds + 2 * ASZ + 8192;

    const int t = threadIdx.x;
    const int lane = t & 63;
    const int w = t >> 6;
    const int wr = (BM == 128) ? (w >> 1) : 0;
    const int wc = (BM == 128) ? (w & 1) : w;
    const int r0 = blockIdx.x * BM;
    const int n0 = blockIdx.y * 128;

    const unsigned short* bhg = Whi + (size_t)blockIdx.y * KS * 4096;
    const unsigned short* blg = Wlo + (size_t)blockIdx.y * KS * 4096;

    f32x4 acc[4][CI];
#pragma unroll
    for (int i = 0; i < 4; ++i)
#pragma unroll
        for (int j = 0; j < CI; ++j) acc[i][j] = (f32x4){0.f, 0.f, 0.f, 0.f};

    for (int ks = 0; ks < KS; ++ks) {
        const int k0 = ks * 32;

        {
            const char* gh = (const char*)(bhg + (size_t)ks * 4096);
            const char* gl = (const char*)(blg + (size_t)ks * 4096);
#pragma unroll
            for (int c = 0; c < 2; ++c) {
                const int ct = w * 2 + c;
                __builtin_amdgcn_global_load_lds(
                    (const __attribute__((address_space(1))) void*)(gh + ct * 1024 + lane * 16),
                    (__attribute__((address_space(3))) void*)(Bhi + ct * 1024), 16, 0, 0);
                __builtin_amdgcn_global_load_lds(
                    (const __attribute__((address_space(1))) void*)(gl + ct * 1024 + lane * 16),
                    (__attribute__((address_space(3))) void*)(Blo + ct * 1024), 16, 0, 0);
            }
        }

        float4 av[BM / 32];
#pragma unroll
        for (int i = 0; i < BM / 32; ++i) {
            const int q = t + i * 256;
            const int row = q >> 3;
            const int kq = (q & 7) * 4;
            const int gr = r0 + row;
            float4 v = make_float4(0.f, 0.f, 0.f, 0.f);
            if (gr < NNODES) v = *(const float4*)(A + (size_t)gr * K + k0 + kq);
            av[i] = v;
        }
#pragma unroll
        for (int i = 0; i < BM / 32; ++i) {
            const int q = t + i * 256;
            const int row = q >> 3;
            const int kq = (q & 7) * 4;
            const int rt = row >> 4, m = row & 15, quad = kq >> 3, j0 = kq & 7;
            const int off = rt * 1024 + (quad * 16 + m) * 16 + j0 * 2;
            const float4 v = av[i];
            ushort4 h, l;
            h.x = f2bf(v.x); l.x = f2bf(v.x - bf2f(h.x));
            h.y = f2bf(v.y); l.y = f2bf(v.y - bf2f(h.y));
            h.z = f2bf(v.z); l.z = f2bf(v.z - bf2f(h.z));
            h.w = f2bf(v.w); l.w = f2bf(v.w - bf2f(h.w));
            *(ushort4*)(Ahi + off) = h;
            *(ushort4*)(Alo + off) = l;
        }
        __syncthreads();

        bf16x8 ah[4], al[4], bh[CI], bl[CI];
#pragma unroll
        for (int i = 0; i < 4; ++i) {
            ah[i] = *(const bf16x8*)(Ahi + (wr * 4 + i) * 1024 + lane * 16);
            al[i] = *(const bf16x8*)(Alo + (wr * 4 + i) * 1024 + lane * 16);
        }
#pragma unroll
        for (int j = 0; j < CI; ++j) {
            bh[j] = *(const bf16x8*)(Bhi + (wc * CI + j) * 1024 + lane * 16);
            bl[j] = *(const bf16x8*)(Blo + (wc * CI + j) * 1024 + lane * 16);
        }
#pragma unroll
        for (int i = 0; i < 4; ++i)
#pragma unroll
            for (int j = 0; j < CI; ++j) {
                acc[i][j] = __builtin_amdgcn_mfma_f32_16x16x32_bf16(ah[i], bh[j], acc[i][j], 0, 0, 0);
                acc[i][j] = __builtin_amdgcn_mfma_f32_16x16x32_bf16(ah[i], bl[j], acc[i][j], 0, 0, 0);
                acc[i][j] = __builtin_amdgcn_mfma_f32_16x16x32_bf16(al[i], bh[j], acc[i][j], 0, 0, 0);
            }
        __syncthreads();
    }

    const int quad = lane >> 4;
    const int cl = lane & 15;
#pragma unroll
    for (int i = 0; i < 4; ++i) {
#pragma unroll
        for (int j = 0; j < CI; ++j) {
            const int colg = n0 + wc * (CI * 16) + j * 16 + cl;
            float bv = 0.f;
            if constexpr (BIAS_RELU) bv = bias[colg];
#pragma unroll
            for (int r = 0; r < 4; ++r) {
                const int rowg = r0 + wr * 64 + i * 16 + quad * 4 + r;
                if (rowg < NNODES) {
                    float v = acc[i][j][r] + bv;
                    if constexpr (BIAS_RELU) v = fmaxf(v, 0.f);
                    C[(size_t)rowg * M + colg] = v;
                    if constexpr (WRITE_BF) Cbf[(size_t)rowg * M + colg] = f2bf(dinv[rowg] * v);
                }
            }
        }
    }
}

// ---------------- fp32 register-tiled GEMM ----------------

template <int BM, int BN, int BK, int TM, int TN, bool HAS_BIAS, bool RELU, bool WRITE_BF>
__global__ __launch_bounds__(256) void gemm_kernel(const float* __restrict__ A,
                                                   const float* __restrict__ W,
                                                   const float* __restrict__ bias,
                                                   float* __restrict__ C,
                                                   unsigned short* __restrict__ Cbf,
                                                   const float* __restrict__ dinv,
                                                   int Nrows, int K, int M) {
    constexpr int TX = BN / TN;
    constexpr int TY = BM / TM;
    static_assert(TX * TY == 256, "thread grid must be 256");
    constexpr int A_LOADS = (BM * BK) / (256 * 4);
    constexpr int W_LOADS = (BN * BK) / (256 * 4);
    static_assert(A_LOADS >= 1 && W_LOADS >= 1, "tile too small");

    const int tid = threadIdx.x;
    const int tx = tid % TX;
    const int ty = tid / TX;
    const int r0 = blockIdx.x * BM;
    const int c0 = blockIdx.y * BN;

    __shared__ float As[BK][BM + 4];
    __shared__ float Ws[BK][BN];

    float acc[TM][TN] = {};

    for (int k0 = 0; k0 < K; k0 += BK) {
#pragma unroll
        for (int l = 0; l < A_LOADS; ++l) {
            const int idx = tid + l * 256;
            const int row = idx / (BK / 4);
            const int kq = idx % (BK / 4);
            float4 v = make_float4(0.f, 0.f, 0.f, 0.f);
            const int gr = r0 + row;
            if (gr < Nrows) v = *(const float4*)(A + (size_t)gr * K + k0 + kq * 4);
            As[kq * 4 + 0][row] = v.x;
            As[kq * 4 + 1][row] = v.y;
            As[kq * 4 + 2][row] = v.z;
            As[kq * 4 + 3][row] = v.w;
        }
#pragma unroll
        for (int l = 0; l < W_LOADS; ++l) {
            const int idx = tid + l * 256;
            const int kk = idx / (BN / 4);
            const int cq = idx % (BN / 4);
            const int gc = c0 + cq * 4;
            float4 v;
            const float* wrow = W + (size_t)(k0 + kk) * M;
            if (gc + 3 < M) {
                v = *(const float4*)(wrow + gc);
            } else {
                v.x = (gc + 0 < M) ? wrow[gc + 0] : 0.f;
                v.y = (gc + 1 < M) ? wrow[gc + 1] : 0.f;
                v.z = (gc + 2 < M) ? wrow[gc + 2] : 0.f;
                v.w = (gc + 3 < M) ? wrow[gc + 3] : 0.f;
            }
            *(float4*)&Ws[kk][cq * 4] = v;
        }
        __syncthreads();

#pragma unroll
        for (int kk = 0; kk < BK; ++kk) {
            float a[TM], b[TN];
#pragma unroll
            for (int i = 0; i < TM; ++i) a[i] = As[kk][ty * TM + i];
#pragma unroll
            for (int j = 0; j < TN; ++j) b[j] = Ws[kk][tx * TN + j];
#pragma unroll
            for (int i = 0; i < TM; ++i)
#pragma unroll
                for (int j = 0; j < TN; ++j) acc[i][j] += a[i] * b[j];
        }
        __syncthreads();
    }

#pragma unroll
    for (int i = 0; i < TM; ++i) {
        const int gr = r0 + ty * TM + i;
        if (gr >= Nrows) continue;
        const float dvr = WRITE_BF ? dinv[gr] : 0.f;
#pragma unroll
        for (int j = 0; j < TN; ++j) {
            const int gc = c0 + tx * TN + j;
            if (gc >= M) continue;
            float v = acc[i][j];
            if constexpr (HAS_BIAS) v += bias[gc];
            if constexpr (RELU) v = fmaxf(v, 0.0f);
            C[(size_t)gr * M + gc] = v;
            if constexpr (WRITE_BF) Cbf[(size_t)gr * M + gc] = f2bf(dvr * v);
        }
    }
}

// ---------------- launch ----------------

extern "C" void kernel_launch(void* const* d_in, const int* in_sizes, int n_in,
                              void* d_out, int out_size, void* d_ws, size_t ws_size,
                              hipStream_t stream) {
    const float* x  = (const float*)d_in[0];
    const int* ei   = (const int*)d_in[1];
    const float* W1 = (const float*)d_in[2];
    const float* b1 = (const float*)d_in[3];
    const float* W2 = (const float*)d_in[4];
    const float* b2 = (const float*)d_in[5];
    const float* W3 = (const float*)d_in[6];
    const float* b3 = (const float*)d_in[7];
    const float* W4 = (const float*)d_in[8];
    const float* b4 = (const float*)d_in[9];
    float* out = (float*)d_out;
    const int* esrc = ei;
    const int* edst = ei + NEDGES;

    char* w = (char*)d_ws;
    auto alloc = [&](size_t bytes) -> void* {
        void* p = (void*)w;
        w += (bytes + 255) & ~(size_t)255;
        return p;
    };
    int* rp     = (int*)alloc((size_t)(NNODES + 1) * 4);
    unsigned short* col = (unsigned short*)alloc((size_t)NEDGES * 2);
    float* dinv = (float*)alloc((size_t)NNODES * 4);
    int* bhist  = (int*)alloc((size_t)NB * 4);
    int* bofs   = (int*)alloc((size_t)(NB + 1) * 4);
    int* gcur   = (int*)alloc((size_t)NB * 4);
    unsigned* gpk = (unsigned*)alloc((size_t)NEDGES * 4);
    unsigned short* W1hi = (unsigned short*)alloc((size_t)128 * 256 * 2);
    unsigned short* W1lo = (unsigned short*)alloc((size_t)128 * 256 * 2);
    unsigned short* W2hi = (unsigned short*)alloc((size_t)256 * 128 * 2);
    unsigned short* W2lo = (unsigned short*)alloc((size_t)256 * 128 * 2);
    float* B0   = (float*)alloc((size_t)NNODES * 256 * 4);
    float* B1   = (float*)alloc((size_t)NNODES * 128 * 4);
    float* B2   = (float*)alloc((size_t)NNODES * 128 * 4);
    unsigned short* xbf  = (unsigned short*)alloc((size_t)NNODES * 128 * 2);
    unsigned short* B1bf = (unsigned short*)alloc((size_t)NNODES * 128 * 2);
    unsigned short* B0bf = (unsigned short*)alloc((size_t)NNODES * 64 * 2);   // premult t3 mirror
    unsigned short* B3bf = (unsigned short*)alloc((size_t)NNODES * 64 * 2);   // premult h3 mirror

    // weight repack (tiny, independent)
    repack_kernel<128, 256><<<(128 * 256 + 255) / 256, 256, 0, stream>>>(W1, W1hi, W1lo);
    repack_kernel<256, 128><<<(256 * 128 + 255) / 256, 256, 0, stream>>>(W2, W2hi, W2lo);

    // bucketed CSR build (5 dispatches) — produces rp, col16, dinv
    zero_kernel<<<1, 256, 0, stream>>>(bhist, NB);
    bucket_count_kernel<<<SCAT_NBLK, 256, 0, stream>>>(edst, bhist);
    bucket_scan_kernel<<<1, 256, 0, stream>>>(bhist, bofs, gcur, rp + NNODES);
    bucket_scatter_kernel<<<SCAT_NBLK, 256, 0, stream>>>(esrc, edst, gcur, gpk);
    csr_fill_kernel<<<NB, 256, 0, stream>>>(gpk, bofs, rp, dinv, col);

    // x mirror premultiplied by dinv (needs dinv)
    cvt_kernel<<<(NNODES * 128 / 4 + 255) / 256, 256, 0, stream>>>(x, dinv, xbf, NNODES * 128 / 4);

    const int aggGrid = (NNODES + 3) / 4;
    const int rowBlks64 = (NNODES + 63) / 64;   // 782

    // Layer 1: aggregate first (dim 128), then MFMA GEMM 128->256 (+bias+relu)
    agg128_kernel<false, false><<<aggGrid, 256, 0, stream>>>(x, xbf, B2, rp, col, dinv, nullptr);
    mfma_gemm_kernel<128, 256, 64, true, false>
        <<<dim3(rowBlks64, 2), 256, 0, stream>>>(B2, W1hi, W1lo, b1, B0, nullptr, nullptr);

    // Layer 2: MFMA GEMM 256->128 (emit premult bf16 mirror), then aggregate (+bias+relu)
    mfma_gemm_kernel<256, 128, 64, false, true>
        <<<dim3(rowBlks64, 1), 256, 0, stream>>>(B0, W2hi, W2lo, nullptr, B1, B1bf, dinv);
    agg128_kernel<true, true><<<aggGrid, 256, 0, stream>>>(B1, B1bf, B2, rp, col, dinv, b2);

    // Layer 3: fp32 GEMM 128->64 (emit premult t3 mirror), aggregate (+bias+relu, emit premult h3 mirror)
    gemm_kernel<64, 64, 16, 4, 4, false, false, true>
        <<<dim3(rowBlks64, 1), 256, 0, stream>>>(B2, W3, nullptr, B0, B0bf, dinv, NNODES, 128, 64);
    agg64_kernel<true, true, true><<<aggGrid, 256, 0, stream>>>(B0, B0bf, B1, B3bf, rp, col, dinv, b3);

    // Layer 4 (aggregate-first via linearity): pure agg64 on h3, then GEMM 64->40 (+bias) -> out
    agg64_kernel<false, false, false><<<aggGrid, 256, 0, stream>>>(B1, B3bf, B2, nullptr, rp, col, dinv, nullptr);
    gemm_kernel<64, 64, 16, 4, 4, true, false, false>
        <<<dim3(rowBlks64, 1), 256, 0, stream>>>(B2, W4, b4, out, nullptr, nullptr, NNODES, 64, 40);
}